// Round 5
// baseline (87.563 us; speedup 1.0000x reference)
//
#include <hip/hip_runtime.h>
#include <math.h>

#define B_N 4096
#define C_N 100
#define D_N 384
#define EPSF 1e-12f
#define NT 8           // class tiles
#define NK (D_N / 16)  // 24 k-steps of 16 dims

// tbl layout (float4 units): tbl4[(k*C_N + c)*8 + seg]     = wc  (w2*center), dims k*16+seg*4..+3
//                            tbl4[(k*C_N + c)*8 + seg + 4] = w2
// -> per k-step a block reads one contiguous ~CT*256B region; inner loop uses ONE base ptr.

// ---------------- prep (fused): tbl, a2[c], present[c], cdist[c]
__global__ __launch_bounds__(128) void k_prep(const float* __restrict__ centers,
                                              const float* __restrict__ cw,
                                              const int* __restrict__ targets,
                                              float* __restrict__ tbl,
                                              float* __restrict__ a2,
                                              float* __restrict__ cdist,
                                              int* __restrict__ present) {
    int c = blockIdx.x, t = threadIdx.x;
    __shared__ __align__(16) float w2s[D_N];
    __shared__ __align__(16) float cs[D_N];
    __shared__ float sred[2], smin[2];
    __shared__ int ps[2];

    float acc = 0.f;
    for (int d = t; d < D_N; d += 128) {
        float wv = exp2f(cw[c * D_N + d]);
        float ce = centers[c * D_N + d];
        float p  = wv * ce;
        w2s[d] = wv;
        cs[d]  = ce;
        int k = d >> 4, seg = (d >> 2) & 3, e = d & 3;
        int base = ((k * C_N + c) * 8 + seg) * 4 + e;
        tbl[base]      = p;   // wc
        tbl[base + 16] = wv;  // w2
        acc = fmaf(p, ce, acc);
    }
    for (int m = 1; m < 64; m <<= 1) acc += __shfl_xor(acc, m, 64);

    int pr = 0;
    for (int i = t; i < B_N; i += 128) pr |= (targets[i] == c) ? 1 : 0;
    pr = __any(pr) ? 1 : 0;

    if ((t & 63) == 0) { sred[t >> 6] = acc; ps[t >> 6] = pr; }
    __syncthreads();   // also publishes w2s / cs
    if (t == 0) { a2[c] = sred[0] + sred[1]; present[c] = ps[0] | ps[1]; }

    // cdist[c] = min over other centers j (thread t = j), weights w2s (center c's)
    float v = INFINITY;
    if (t < C_N && t != c) {
        float ad = 0.f;
        const float4* cj = (const float4*)(centers + (size_t)t * D_N);
        const float4* ci = (const float4*)cs;
        const float4* wi = (const float4*)w2s;
        for (int k = 0; k < D_N / 4; k++) {
            float4 a = ci[k], b = cj[k], wv = wi[k];
            float dd;
            dd = a.x - b.x; ad = fmaf(wv.x * dd, dd, ad);
            dd = a.y - b.y; ad = fmaf(wv.y * dd, dd, ad);
            dd = a.z - b.z; ad = fmaf(wv.z * dd, dd, ad);
            dd = a.w - b.w; ad = fmaf(wv.w * dd, dd, ad);
        }
        v = sqrtf(fmaxf(ad, 0.f));
    }
    for (int m = 1; m < 64; m <<= 1) v = fminf(v, __shfl_xor(v, m, 64));
    if ((t & 63) == 0) smin[t >> 6] = v;
    __syncthreads();
    if (t == 0) cdist[c] = fminf(smin[0], smin[1]);
}

// ---------------- main: block = 16 rows x CT classes (CT = 13 or 12), 4 waves.
// wave w owns classes c0+w+4j (j < nc, nc = ceil((CT-w)/4) <= 4).
// lane: r = l&15 (row), seg = l>>4 (dim quarter). grid = 256 rowtiles * 8 ctiles = 2048.
__global__ __launch_bounds__(256, 2) void k_main(const float* __restrict__ inputs,
                                                 const int* __restrict__ targets,
                                                 const float* __restrict__ tbl,
                                                 const float* __restrict__ a2,
                                                 const int* __restrict__ present,
                                                 float2* __restrict__ apan) {
    int tid = threadIdx.x;
    int w   = tid >> 6;
    int l   = tid & 63;
    int r   = l & 15;
    int seg = l >> 4;
    int rowtile = blockIdx.x >> 3;
    int ctile   = blockIdx.x & 7;
    int row = rowtile * 16 + r;
    int ti  = targets[row];
    int c0  = (ctile < 4) ? ctile * 13 : 52 + (ctile - 4) * 12;
    int CT  = (ctile < 4) ? 13 : 12;
    int nc  = (CT - w + 3) >> 2;   // 4,3,3,3 or 3,3,3,3

    const float*  xb = inputs + (size_t)row * D_N + seg * 4;
    const float4* tb = (const float4*)tbl + (size_t)(c0 + w) * 8 + seg;

    float cr[4], qd[4];
#pragma unroll
    for (int j = 0; j < 4; j++) { cr[j] = 0.f; qd[j] = 0.f; }

#pragma unroll
    for (int k = 0; k < NK; k++) {
        float4 x  = *(const float4*)(xb + k * 16);
        float4 x2 = make_float4(x.x * x.x, x.y * x.y, x.z * x.z, x.w * x.w);
        const float4* tk = tb + (size_t)k * C_N * 8;
#pragma unroll
        for (int j = 0; j < 4; j++) {
            if (j < nc) {
                float4 wcv = tk[j * 32];       // class c0+w+4j, wc part
                float4 w2v = tk[j * 32 + 4];   // w2 part
                float c1 = cr[j], q1 = qd[j];
                c1 = fmaf(x.x,  wcv.x, c1);
                c1 = fmaf(x.y,  wcv.y, c1);
                c1 = fmaf(x.z,  wcv.z, c1);
                c1 = fmaf(x.w,  wcv.w, c1);
                q1 = fmaf(x2.x, w2v.x, q1);
                q1 = fmaf(x2.y, w2v.y, q1);
                q1 = fmaf(x2.z, w2v.z, q1);
                q1 = fmaf(x2.w, w2v.w, q1);
                cr[j] = c1; qd[j] = q1;
            }
        }
    }

    float vap = -INFINITY, vmin = INFINITY;
#pragma unroll
    for (int j = 0; j < 4; j++) {
        if (j < nc) {
            int c = c0 + w + 4 * j;
            float scr = cr[j];
            scr += __shfl_xor(scr, 16, 64);
            scr += __shfl_xor(scr, 32, 64);
            float sqd = qd[j];
            sqd += __shfl_xor(sqd, 16, 64);
            sqd += __shfl_xor(sqd, 32, 64);
            float d2 = a2[c] - 2.f * scr + sqd;
            float g  = sqrtf(fmaxf(d2, EPSF));
            if (c == ti) vap = g;
            else if (present[c]) vmin = fminf(vmin, g);
        }
    }

    __shared__ float sap[4][16], san[4][16];
    if (l < 16) { sap[w][r] = vap; san[w][r] = vmin; }
    __syncthreads();
    if (tid < 16) {
        float ap = fmaxf(fmaxf(sap[0][tid], sap[1][tid]), fmaxf(sap[2][tid], sap[3][tid]));
        float an = fminf(fminf(san[0][tid], san[1][tid]), fminf(san[2][tid], san[3][tid]));
        apan[(size_t)ctile * B_N + rowtile * 16 + tid] = make_float2(ap, an);
    }
}

// ---------------- final: combine 8 class tiles, compute loss, reduce sum
__global__ __launch_bounds__(1024) void k_final(const float2* __restrict__ apan,
                                                const float* __restrict__ cdist,
                                                const int* __restrict__ targets,
                                                float* __restrict__ out) {
    int tid = threadIdx.x;
    float sum = 0.f;
    for (int row = tid; row < B_N; row += 1024) {
        float ap = -INFINITY, an = INFINITY;
#pragma unroll
        for (int t = 0; t < NT; t++) {
            float2 v = apan[(size_t)t * B_N + row];
            ap = fmaxf(ap, v.x);
            an = fminf(an, v.y);
        }
        float cc = cdist[targets[row]];
        sum += (an >= cc) ? ap : (ap - an + cc);
    }
    for (int m = 1; m < 64; m <<= 1) sum += __shfl_xor(sum, m, 64);
    __shared__ float sw[16];
    if ((tid & 63) == 0) sw[tid >> 6] = sum;
    __syncthreads();
    if (tid < 64) {
        float v = (tid < 16) ? sw[tid] : 0.f;
        for (int m = 1; m < 16; m <<= 1) v += __shfl_xor(v, m, 64);
        if (tid == 0) out[0] = v / (float)B_N;
    }
}

extern "C" void kernel_launch(void* const* d_in, const int* in_sizes, int n_in,
                              void* d_out, int out_size, void* d_ws, size_t ws_size,
                              hipStream_t stream) {
    const float* inputs  = (const float*)d_in[0];
    const float* centers = (const float*)d_in[1];
    const float* cw      = (const float*)d_in[2];
    const int*   targets = (const int*)d_in[3];
    (void)in_sizes; (void)n_in; (void)out_size; (void)ws_size;

    char* ws = (char*)d_ws;
    float*  tbl     = (float*)(ws + 0);         // 24*100*8 float4 = 307200 B
    float2* apan    = (float2*)(ws + 307200);   // 8*4096*8 = 262144 B
    float*  a2      = (float*)(ws + 569344);    // 100*4
    float*  cdist   = (float*)(ws + 569856);    // 100*4
    int*    present = (int*)(ws + 570368);      // 100*4

    k_prep<<<C_N, 128, 0, stream>>>(centers, cw, targets, tbl, a2, cdist, present);
    k_main<<<2048, 256, 0, stream>>>(inputs, targets, tbl, a2, present, apan);
    k_final<<<1, 1024, 0, stream>>>(apan, cdist, targets, (float*)d_out);
}

// Round 6
// 59.249 us; speedup vs baseline: 1.4779x; 1.4779x over previous
//
#include <hip/hip_runtime.h>
#include <math.h>

#define B_N 4096
#define C_N 100
#define D_N 384
#define EPSF 1e-12f
#define NT 8           // class tiles
#define NK (D_N / 16)  // 24 k-steps of 16 dims
#define CTMAX 13

// tbl layout, CLASS-major (float4 units):
//   tbl4[(c*NK + k)*8 + seg]     = wc  (w2*center), dims k*16 + seg*4 .. +3
//   tbl4[(c*NK + k)*8 + seg + 4] = w2
// -> per-block class slice [c0, c0+CT) is one contiguous region (CT*3072 B) for LDS staging.

// ---------------- prep (fused): tbl, a2[c], present[c], cdist[c]
__global__ __launch_bounds__(128) void k_prep(const float* __restrict__ centers,
                                              const float* __restrict__ cw,
                                              const int* __restrict__ targets,
                                              float* __restrict__ tbl,
                                              float* __restrict__ a2,
                                              float* __restrict__ cdist,
                                              int* __restrict__ present) {
    int c = blockIdx.x, t = threadIdx.x;
    __shared__ __align__(16) float w2s[D_N];
    __shared__ __align__(16) float cs[D_N];
    __shared__ float sred[2], smin[2];
    __shared__ int ps[2];

    float acc = 0.f;
    for (int d = t; d < D_N; d += 128) {
        float wv = exp2f(cw[c * D_N + d]);
        float ce = centers[c * D_N + d];
        float p  = wv * ce;
        w2s[d] = wv;
        cs[d]  = ce;
        int k = d >> 4, seg = (d >> 2) & 3, e = d & 3;
        int base = ((c * NK + k) * 8 + seg) * 4 + e;
        tbl[base]      = p;   // wc
        tbl[base + 16] = wv;  // w2
        acc = fmaf(p, ce, acc);
    }
    for (int m = 1; m < 64; m <<= 1) acc += __shfl_xor(acc, m, 64);

    int pr = 0;
    for (int i = t; i < B_N; i += 128) pr |= (targets[i] == c) ? 1 : 0;
    pr = __any(pr) ? 1 : 0;

    if ((t & 63) == 0) { sred[t >> 6] = acc; ps[t >> 6] = pr; }
    __syncthreads();   // publishes w2s / cs
    if (t == 0) { a2[c] = sred[0] + sred[1]; present[c] = ps[0] | ps[1]; }

    // cdist[c] = min over other centers j (thread t = j), weights w2s (center c's)
    float v = INFINITY;
    if (t < C_N && t != c) {
        float ad = 0.f;
        const float4* cj = (const float4*)(centers + (size_t)t * D_N);
        const float4* ci = (const float4*)cs;
        const float4* wi = (const float4*)w2s;
        for (int k = 0; k < D_N / 4; k++) {
            float4 a = ci[k], b = cj[k], wv = wi[k];
            float dd;
            dd = a.x - b.x; ad = fmaf(wv.x * dd, dd, ad);
            dd = a.y - b.y; ad = fmaf(wv.y * dd, dd, ad);
            dd = a.z - b.z; ad = fmaf(wv.z * dd, dd, ad);
            dd = a.w - b.w; ad = fmaf(wv.w * dd, dd, ad);
        }
        v = sqrtf(fmaxf(ad, 0.f));
    }
    for (int m = 1; m < 64; m <<= 1) v = fminf(v, __shfl_xor(v, m, 64));
    if ((t & 63) == 0) smin[t >> 6] = v;
    __syncthreads();
    if (t == 0) cdist[c] = fminf(smin[0], smin[1]);
}

// ---------------- main: block = 16 rows x CT classes (13 or 12), 4 waves.
// Table slice staged in LDS once per block; k-loop reads tables from LDS only.
// wave w owns classes c0+w+4j (j < nc). lane: r = l&15 (row), seg = l>>4 (dim quarter).
__global__ __launch_bounds__(256, 2) void k_main(const float* __restrict__ inputs,
                                                 const int* __restrict__ targets,
                                                 const float* __restrict__ tbl,
                                                 const float* __restrict__ a2,
                                                 const int* __restrict__ present,
                                                 float2* __restrict__ apan) {
    __shared__ __align__(16) float4 tb[CTMAX * NK * 8];   // 39936 B
    __shared__ float sap[4][16], san[4][16];

    int tid = threadIdx.x;
    int w   = tid >> 6;
    int l   = tid & 63;
    int r   = l & 15;
    int seg = l >> 4;
    int rowtile = blockIdx.x >> 3;
    int ctile   = blockIdx.x & 7;
    int row = rowtile * 16 + r;
    int ti  = targets[row];
    int c0  = (ctile < 4) ? ctile * 13 : 52 + (ctile - 4) * 12;
    int CT  = (ctile < 4) ? 13 : 12;
    int nc  = (CT - w + 3) >> 2;   // 4,3,3,3 or 3,3,3,3

    // ---- stage class slice: CT*NK*8 float4s, contiguous in global
    {
        const float4* gsrc = (const float4*)tbl + (size_t)c0 * NK * 8;
        int total = CT * NK * 8;   // 2496 or 2304
        for (int q = tid; q < total; q += 256) tb[q] = gsrc[q];
    }
    __syncthreads();

    const float*  xb = inputs + (size_t)row * D_N + seg * 4;
    const float4* tw = tb + w * NK * 8 + seg;   // class c_local = w+4j at +j*4*NK*8

    float cr[4], qd[4];
#pragma unroll
    for (int j = 0; j < 4; j++) { cr[j] = 0.f; qd[j] = 0.f; }

#pragma unroll
    for (int k = 0; k < NK; k++) {
        float4 x  = *(const float4*)(xb + k * 16);
        float4 x2 = make_float4(x.x * x.x, x.y * x.y, x.z * x.z, x.w * x.w);
#pragma unroll
        for (int j = 0; j < 4; j++) {
            if (j < nc) {
                float4 wcv = tw[j * (4 * NK * 8) + k * 8];       // wc
                float4 w2v = tw[j * (4 * NK * 8) + k * 8 + 4];   // w2
                float c1 = cr[j], q1 = qd[j];
                c1 = fmaf(x.x,  wcv.x, c1);
                c1 = fmaf(x.y,  wcv.y, c1);
                c1 = fmaf(x.z,  wcv.z, c1);
                c1 = fmaf(x.w,  wcv.w, c1);
                q1 = fmaf(x2.x, w2v.x, q1);
                q1 = fmaf(x2.y, w2v.y, q1);
                q1 = fmaf(x2.z, w2v.z, q1);
                q1 = fmaf(x2.w, w2v.w, q1);
                cr[j] = c1; qd[j] = q1;
            }
        }
    }

    float vap = -INFINITY, vmin = INFINITY;
#pragma unroll
    for (int j = 0; j < 4; j++) {
        if (j < nc) {
            int c = c0 + w + 4 * j;
            float scr = cr[j];
            scr += __shfl_xor(scr, 16, 64);
            scr += __shfl_xor(scr, 32, 64);
            float sqd = qd[j];
            sqd += __shfl_xor(sqd, 16, 64);
            sqd += __shfl_xor(sqd, 32, 64);
            float d2 = a2[c] - 2.f * scr + sqd;
            float g  = sqrtf(fmaxf(d2, EPSF));
            if (c == ti) vap = g;
            else if (present[c]) vmin = fminf(vmin, g);
        }
    }

    if (l < 16) { sap[w][r] = vap; san[w][r] = vmin; }
    __syncthreads();
    if (tid < 16) {
        float ap = fmaxf(fmaxf(sap[0][tid], sap[1][tid]), fmaxf(sap[2][tid], sap[3][tid]));
        float an = fminf(fminf(san[0][tid], san[1][tid]), fminf(san[2][tid], san[3][tid]));
        apan[(size_t)ctile * B_N + rowtile * 16 + tid] = make_float2(ap, an);
    }
}

// ---------------- final: combine 8 class tiles, compute loss, reduce sum
__global__ __launch_bounds__(1024) void k_final(const float2* __restrict__ apan,
                                                const float* __restrict__ cdist,
                                                const int* __restrict__ targets,
                                                float* __restrict__ out) {
    int tid = threadIdx.x;
    float sum = 0.f;
    for (int row = tid; row < B_N; row += 1024) {
        float ap = -INFINITY, an = INFINITY;
#pragma unroll
        for (int t = 0; t < NT; t++) {
            float2 v = apan[(size_t)t * B_N + row];
            ap = fmaxf(ap, v.x);
            an = fminf(an, v.y);
        }
        float cc = cdist[targets[row]];
        sum += (an >= cc) ? ap : (ap - an + cc);
    }
    for (int m = 1; m < 64; m <<= 1) sum += __shfl_xor(sum, m, 64);
    __shared__ float sw[16];
    if ((tid & 63) == 0) sw[tid >> 6] = sum;
    __syncthreads();
    if (tid < 64) {
        float v = (tid < 16) ? sw[tid] : 0.f;
        for (int m = 1; m < 16; m <<= 1) v += __shfl_xor(v, m, 64);
        if (tid == 0) out[0] = v / (float)B_N;
    }
}

extern "C" void kernel_launch(void* const* d_in, const int* in_sizes, int n_in,
                              void* d_out, int out_size, void* d_ws, size_t ws_size,
                              hipStream_t stream) {
    const float* inputs  = (const float*)d_in[0];
    const float* centers = (const float*)d_in[1];
    const float* cw      = (const float*)d_in[2];
    const int*   targets = (const int*)d_in[3];
    (void)in_sizes; (void)n_in; (void)out_size; (void)ws_size;

    char* ws = (char*)d_ws;
    float*  tbl     = (float*)(ws + 0);         // 100*24*8 float4 = 307200 B
    float2* apan    = (float2*)(ws + 307200);   // 8*4096*8 = 262144 B
    float*  a2      = (float*)(ws + 569344);    // 100*4
    float*  cdist   = (float*)(ws + 569856);    // 100*4
    int*    present = (int*)(ws + 570368);      // 100*4

    k_prep<<<C_N, 128, 0, stream>>>(centers, cw, targets, tbl, a2, cdist, present);
    k_main<<<2048, 256, 0, stream>>>(inputs, targets, tbl, a2, present, apan);
    k_final<<<1, 1024, 0, stream>>>(apan, cdist, targets, (float*)d_out);
}